// Round 1
// baseline (267.024 us; speedup 1.0000x reference)
//
#include <hip/hip_runtime.h>

#define HH 128
#define WW 128
#define BB 64
#define OO 32

// Setup: per-o affine coefficients, pre-folded with the pixel-space transform:
//   x = (a00*Xg + a01*Yg + tx + 1) * 63.5  =  (a00*63.5)*Xg + (a01*63.5)*Yg + (tx+1)*63.5
__global__ void coeff_kernel(const float* __restrict__ eps,
                             const float* __restrict__ tmin,
                             const float* __restrict__ tmax,
                             float* __restrict__ coef) {
    int o = threadIdx.x;
    if (o >= OO) return;
    float th[7];
#pragma unroll
    for (int i = 0; i < 7; ++i) {
        float mn = tmin[i], mx = tmax[i];
        th[i] = mn + (mx - mn) * eps[o * 7 + i];
    }
    float ang = th[0], sx = th[1], sy = th[2], px = th[3], py = th[4], tx = th[5], ty = th[6];
    float c = cosf(ang), s = sinf(ang);
    float a00 = c * sx - s * py;
    float a01 = c * px - s * sy;
    float a10 = s * sx + c * py;
    float a11 = s * px + c * sy;
    const float half = 0.5f * (WW - 1);  // 63.5, H==W so same for y
    coef[o * 8 + 0] = a00 * half;
    coef[o * 8 + 1] = a01 * half;
    coef[o * 8 + 2] = (tx + 1.0f) * half;
    coef[o * 8 + 3] = a10 * half;
    coef[o * 8 + 4] = a11 * half;
    coef[o * 8 + 5] = (ty + 1.0f) * half;
}

// One block = one (o, b, 8-row group). 256 threads; each thread -> 4 consecutive
// w pixels, one float4 store. Gathers from a single 64 KiB image (L1/L2 resident).
__launch_bounds__(256, 4)
__global__ void sample_kernel(const float* __restrict__ X,
                              const float* __restrict__ coef,
                              float* __restrict__ out) {
    const int bid  = blockIdx.x;
    const int o    = bid >> 10;          // B*(H/8) = 64*16 = 1024 blocks per o
    const int b    = (bid >> 4) & 63;
    const int hblk = bid & 15;
    const int tid  = threadIdx.x;
    const int hsub = tid >> 5;           // 0..7
    const int w4   = (tid & 31) << 2;    // 0,4,...,124
    const int h    = hblk * 8 + hsub;

    // o is block-uniform -> compiler scalarizes these loads
    const float cx0 = coef[o * 8 + 0];
    const float cx1 = coef[o * 8 + 1];
    const float cxt = coef[o * 8 + 2];
    const float cy0 = coef[o * 8 + 3];
    const float cy1 = coef[o * 8 + 4];
    const float cyt = coef[o * 8 + 5];

    const float step = 2.0f / 127.0f;
    const float Yg = -1.0f + h * step;
    const float bx = cx1 * Yg + cxt;     // row-constant part of x
    const float by = cy1 * Yg + cyt;     // row-constant part of y

    const float* __restrict__ img = X + b * (HH * WW);

    float4 r;
    float* rp = &r.x;
#pragma unroll
    for (int j = 0; j < 4; ++j) {
        const int w = w4 + j;
        const float Xg = -1.0f + w * step;
        const float x = cx0 * Xg + bx;
        const float y = cy0 * Xg + by;
        const float x0f = floorf(x);
        const float y0f = floorf(y);
        const float wx = x - x0f;
        const float wy = y - y0f;
        const int ix = (int)x0f;
        const int iy = (int)y0f;
        const int x0 = min(max(ix, 0), WW - 1);
        const int x1 = min(max(ix + 1, 0), WW - 1);
        const int y0 = min(max(iy, 0), HH - 1);
        const int y1 = min(max(iy + 1, 0), HH - 1);
        const float Ia = img[y0 * WW + x0];
        const float Ib = img[y1 * WW + x0];
        const float Ic = img[y0 * WW + x1];
        const float Id = img[y1 * WW + x1];
        const float owx = 1.0f - wx;
        const float owy = 1.0f - wy;
        rp[j] = Ia * (owx * owy) + Ib * (owx * wy) + Ic * (wx * owy) + Id * (wx * wy);
    }

    const size_t oidx = (((size_t)(o * BB + b) * HH + h) * WW + w4);
    *(float4*)(out + oidx) = r;
}

extern "C" void kernel_launch(void* const* d_in, const int* in_sizes, int n_in,
                              void* d_out, int out_size, void* d_ws, size_t ws_size,
                              hipStream_t stream) {
    const float* X    = (const float*)d_in[0];
    const float* eps  = (const float*)d_in[1];
    const float* tmin = (const float*)d_in[2];
    const float* tmax = (const float*)d_in[3];
    float* out  = (float*)d_out;
    float* coef = (float*)d_ws;  // 32*8 floats = 1 KiB

    coeff_kernel<<<1, 64, 0, stream>>>(eps, tmin, tmax, coef);

    const int nblocks = OO * BB * (HH / 8);  // 32768
    sample_kernel<<<nblocks, 256, 0, stream>>>(X, coef, out);
}

// Round 2
// 172.414 us; speedup vs baseline: 1.5487x; 1.5487x over previous
//
#include <hip/hip_runtime.h>

#define HH 128
#define WW 128
#define BB 64
#define OO 32

// Per-o affine coefficients, pre-folded with the pixel-space transform:
//   x = (a00*Xg + a01*Yg + tx + 1) * 63.5
__global__ void coeff_kernel(const float* __restrict__ eps,
                             const float* __restrict__ tmin,
                             const float* __restrict__ tmax,
                             float* __restrict__ coef) {
    int o = threadIdx.x;
    if (o >= OO) return;
    float th[7];
#pragma unroll
    for (int i = 0; i < 7; ++i) {
        float mn = tmin[i], mx = tmax[i];
        th[i] = mn + (mx - mn) * eps[o * 7 + i];
    }
    float ang = th[0], sx = th[1], sy = th[2], px = th[3], py = th[4], tx = th[5], ty = th[6];
    float c = cosf(ang), s = sinf(ang);
    float a00 = c * sx - s * py;
    float a01 = c * px - s * sy;
    float a10 = s * sx + c * py;
    float a11 = s * px + c * sy;
    const float half = 0.5f * (WW - 1);  // 63.5
    coef[o * 8 + 0] = a00 * half;
    coef[o * 8 + 1] = a01 * half;
    coef[o * 8 + 2] = (tx + 1.0f) * half;
    coef[o * 8 + 3] = a10 * half;
    coef[o * 8 + 4] = a11 * half;
    coef[o * 8 + 5] = (ty + 1.0f) * half;
}

// One block = one (o,b). Full 64 KiB image staged in LDS; bilinear gathers hit
// LDS (lane-adjacent w -> addr stride ~a00 floats -> mostly <=2-way bank alias,
// free per m136). 2 blocks/CU (LDS-capped). Thread t owns column w=t&127,
// rows h = (t>>7) + 2i  -> wave stores are 256B contiguous.
__launch_bounds__(256, 1)
__global__ void sample_kernel(const float* __restrict__ X,
                              const float* __restrict__ coef,
                              float* __restrict__ out) {
    __shared__ float img[HH * WW];  // 64 KiB

    const int bid = blockIdx.x;
    const int o   = bid & (OO - 1);   // consecutive blocks share b -> L2 reuse on staging
    const int b   = bid >> 5;
    const int tid = threadIdx.x;

    // Stage image b -> LDS, coalesced float4
    {
        const float4* __restrict__ src = (const float4*)(X + b * (HH * WW));
        float4* dst = (float4*)img;
#pragma unroll
        for (int i = 0; i < 16; ++i)
            dst[tid + i * 256] = src[tid + i * 256];
    }

    // Block-uniform coefficients (scalarized)
    const float cx0 = coef[o * 8 + 0];
    const float cx1 = coef[o * 8 + 1];
    const float cxt = coef[o * 8 + 2];
    const float cy0 = coef[o * 8 + 3];
    const float cy1 = coef[o * 8 + 4];
    const float cyt = coef[o * 8 + 5];

    __syncthreads();

    const int w  = tid & (WW - 1);
    const int h0 = tid >> 7;                 // 0 or 1
    const float step = 2.0f / 127.0f;
    const float Xg = -1.0f + w * step;
    const float bxw = fmaf(cx0, Xg, cxt);    // column-constant parts
    const float byw = fmaf(cy0, Xg, cyt);

    float* __restrict__ outp = out + ((size_t)(o * BB + b) * (HH * WW)) + w;

#pragma unroll 8
    for (int i = 0; i < 64; ++i) {
        const int h = h0 + i * 2;
        const float Yg = -1.0f + h * step;
        const float x = fmaf(cx1, Yg, bxw);
        const float y = fmaf(cy1, Yg, byw);

        const float x0f = floorf(x);
        const float y0f = floorf(y);
        const float wx = x - x0f;
        const float wy = y - y0f;
        const int ix = (int)x0f;
        const int iy = (int)y0f;
        const int x0 = min(max(ix, 0), WW - 1);
        const int x1 = min(max(ix + 1, 0), WW - 1);
        const int y0 = min(max(iy, 0), HH - 1);
        const int y1 = min(max(iy + 1, 0), HH - 1);

        const int r0 = y0 << 7;
        const int r1 = y1 << 7;
        const float Ia = img[r0 + x0];
        const float Ic = img[r0 + x1];
        const float Ib = img[r1 + x0];
        const float Id = img[r1 + x1];

        const float owx = 1.0f - wx;
        const float owy = 1.0f - wy;
        const float top = fmaf(Ic, wx, Ia * owx);
        const float bot = fmaf(Id, wx, Ib * owx);
        outp[h * WW] = fmaf(bot, wy, top * owy);
    }
}

extern "C" void kernel_launch(void* const* d_in, const int* in_sizes, int n_in,
                              void* d_out, int out_size, void* d_ws, size_t ws_size,
                              hipStream_t stream) {
    const float* X    = (const float*)d_in[0];
    const float* eps  = (const float*)d_in[1];
    const float* tmin = (const float*)d_in[2];
    const float* tmax = (const float*)d_in[3];
    float* out  = (float*)d_out;
    float* coef = (float*)d_ws;  // 32*8 floats

    coeff_kernel<<<1, 64, 0, stream>>>(eps, tmin, tmax, coef);

    const int nblocks = OO * BB;  // 2048
    sample_kernel<<<nblocks, 256, 0, stream>>>(X, coef, out);
}

// Round 3
// 158.264 us; speedup vs baseline: 1.6872x; 1.0894x over previous
//
#include <hip/hip_runtime.h>

#define HH 128
#define WW 128
#define BB 64
#define OO 32

// Per-o affine coefficients, pre-folded with the pixel-space transform:
//   x = (a00*Xg + a01*Yg + tx + 1) * 63.5
__global__ void coeff_kernel(const float* __restrict__ eps,
                             const float* __restrict__ tmin,
                             const float* __restrict__ tmax,
                             float* __restrict__ coef) {
    int o = threadIdx.x;
    if (o >= OO) return;
    float th[7];
#pragma unroll
    for (int i = 0; i < 7; ++i) {
        float mn = tmin[i], mx = tmax[i];
        th[i] = mn + (mx - mn) * eps[o * 7 + i];
    }
    float ang = th[0], sx = th[1], sy = th[2], px = th[3], py = th[4], tx = th[5], ty = th[6];
    float c = cosf(ang), s = sinf(ang);
    float a00 = c * sx - s * py;
    float a01 = c * px - s * sy;
    float a10 = s * sx + c * py;
    float a11 = s * px + c * sy;
    const float half = 0.5f * (WW - 1);  // 63.5
    coef[o * 8 + 0] = a00 * half;
    coef[o * 8 + 1] = a01 * half;
    coef[o * 8 + 2] = (tx + 1.0f) * half;
    coef[o * 8 + 3] = a10 * half;
    coef[o * 8 + 4] = a11 * half;
    coef[o * 8 + 5] = (ty + 1.0f) * half;
}

// Block = (b, group of 4 o's). 512 blocks x 512 threads -> exactly 2 resident
// blocks/CU (64 KiB LDS each), 16 waves/CU. Image staged once per 4 o's.
// Coordinate clamp into [0, 126.99999] replaces the reference's index clamp
// (equivalent to ~1e-5 relative tap weight; always in-bounds) so each bilinear
// row-pair compiles to one ds_read2_b32 (offsets +0,+1 / +128,+129).
__launch_bounds__(512)
__global__ void sample_kernel(const float* __restrict__ X,
                              const float* __restrict__ coef,
                              float* __restrict__ out) {
    __shared__ float img[HH * WW];  // 64 KiB

    const int bid = blockIdx.x;
    const int og  = bid & 7;          // consecutive blocks share b -> L2 reuse
    const int b   = bid >> 3;
    const int tid = threadIdx.x;

    // Stage image b -> LDS, coalesced float4 (8 per thread)
    {
        const float4* __restrict__ src = (const float4*)(X + b * (HH * WW));
        float4* dst = (float4*)img;
#pragma unroll
        for (int i = 0; i < 8; ++i)
            dst[tid + i * 512] = src[tid + i * 512];
    }
    __syncthreads();

    const int w  = tid & (WW - 1);
    const int h0 = tid >> 7;                 // 0..3
    const float step = 2.0f / 127.0f;
    const float Xg = -1.0f + w * step;
    const float hi = 126.999992f;            // nextbelow(127): forces wx=0 at the edge

#pragma unroll
    for (int j = 0; j < 4; ++j) {
        const int o = og * 4 + j;            // block-uniform -> scalar loads
        const float cx0 = coef[o * 8 + 0];
        const float cx1 = coef[o * 8 + 1];
        const float cxt = coef[o * 8 + 2];
        const float cy0 = coef[o * 8 + 3];
        const float cy1 = coef[o * 8 + 4];
        const float cyt = coef[o * 8 + 5];

        const float bxw = fmaf(cx0, Xg, cxt);   // column-constant parts
        const float byw = fmaf(cy0, Xg, cyt);

        float* __restrict__ outp = out + ((size_t)(o * BB + b) * (HH * WW)) + w;

#pragma unroll 8
        for (int i = 0; i < 32; ++i) {
            const int h = h0 + i * 4;
            const float Yg = -1.0f + h * step;
            float x = fmaf(cx1, Yg, bxw);
            float y = fmaf(cy1, Yg, byw);
            x = fminf(fmaxf(x, 0.0f), hi);
            y = fminf(fmaxf(y, 0.0f), hi);

            const float x0f = floorf(x);
            const float y0f = floorf(y);
            const float wx = x - x0f;
            const float wy = y - y0f;
            const int idx = ((int)y0f << 7) + (int)x0f;

            const float Ia = img[idx];
            const float Ic = img[idx + 1];        // ds_read2_b32 with Ia
            const float Ib = img[idx + WW];
            const float Id = img[idx + WW + 1];   // ds_read2_b32 with Ib

            const float top = fmaf(wx, Ic - Ia, Ia);
            const float bot = fmaf(wx, Id - Ib, Ib);
            outp[h * WW] = fmaf(wy, bot - top, top);
        }
    }
}

extern "C" void kernel_launch(void* const* d_in, const int* in_sizes, int n_in,
                              void* d_out, int out_size, void* d_ws, size_t ws_size,
                              hipStream_t stream) {
    const float* X    = (const float*)d_in[0];
    const float* eps  = (const float*)d_in[1];
    const float* tmin = (const float*)d_in[2];
    const float* tmax = (const float*)d_in[3];
    float* out  = (float*)d_out;
    float* coef = (float*)d_ws;  // 32*8 floats

    coeff_kernel<<<1, 64, 0, stream>>>(eps, tmin, tmax, coef);

    const int nblocks = BB * 8;  // 512: 2 per CU, LDS-capped residency
    sample_kernel<<<nblocks, 512, 0, stream>>>(X, coef, out);
}

// Round 4
// 153.780 us; speedup vs baseline: 1.7364x; 1.0292x over previous
//
#include <hip/hip_runtime.h>

#define HH 128
#define WW 128
#define BB 64
#define OO 32

// Single fused kernel. Block = (b, group of 4 o's): 512 blocks x 1024 threads
// -> exactly 2 resident blocks/CU (2 x 64 KiB LDS = 128 <= 160 KiB), 32
// waves/CU (full occupancy; __launch_bounds__(1024,8) caps VGPR at 64).
// Threads 0..3 compute the 4 per-o affine coefficient sets (pre-folded with
// the pixel-space transform) into LDS, reusing the staging barrier.
// Coordinate clamp into [0, 126.99999] replaces the reference's index clamp
// (equivalent within ~1e-5 tap weight; keeps +1/+128 taps in-bounds) so each
// bilinear row-pair compiles to one ds_read2_b32.
__launch_bounds__(1024, 8)
__global__ void sample_kernel(const float* __restrict__ X,
                              const float* __restrict__ eps,
                              const float* __restrict__ tmin,
                              const float* __restrict__ tmax,
                              float* __restrict__ out) {
    __shared__ float img[HH * WW];   // 64 KiB
    __shared__ float scoef[4][6];

    const int bid = blockIdx.x;
    const int og  = bid & 7;          // consecutive blocks share b -> L2 reuse
    const int b   = bid >> 3;
    const int tid = threadIdx.x;

    if (tid < 4) {
        const int o = og * 4 + tid;
        float th[7];
#pragma unroll
        for (int i = 0; i < 7; ++i) {
            const float mn = tmin[i], mx = tmax[i];
            th[i] = mn + (mx - mn) * eps[o * 7 + i];
        }
        const float ang = th[0], sx = th[1], sy = th[2], px = th[3],
                    py = th[4], tx = th[5], ty = th[6];
        const float c = cosf(ang), s = sinf(ang);
        const float half = 0.5f * (WW - 1);  // 63.5
        scoef[tid][0] = (c * sx - s * py) * half;   // cx0
        scoef[tid][1] = (c * px - s * sy) * half;   // cx1
        scoef[tid][2] = (tx + 1.0f) * half;         // cxt
        scoef[tid][3] = (s * sx + c * py) * half;   // cy0
        scoef[tid][4] = (s * px + c * sy) * half;   // cy1
        scoef[tid][5] = (ty + 1.0f) * half;         // cyt
    }

    // Stage image b -> LDS, coalesced float4 (4 per thread)
    {
        const float4* __restrict__ src = (const float4*)(X + b * (HH * WW));
        float4* dst = (float4*)img;
#pragma unroll
        for (int i = 0; i < 4; ++i)
            dst[tid + i * 1024] = src[tid + i * 1024];
    }
    __syncthreads();

    const int w  = tid & (WW - 1);
    const int h0 = tid >> 7;                 // 0..7; wave = 256B-contiguous row chunk
    const float step  = 2.0f / 127.0f;
    const float hstep = 8.0f * step;         // row stride of the i-loop
    const float Xg  = -1.0f + w * step;
    const float Yg0 = -1.0f + h0 * step;
    const float hi  = 126.999992f;           // nextbelow(127)

#pragma unroll
    for (int j = 0; j < 4; ++j) {
        const int o = og * 4 + j;
        const float cx0 = scoef[j][0];
        const float cx1 = scoef[j][1];
        const float cxt = scoef[j][2];
        const float cy0 = scoef[j][3];
        const float cy1 = scoef[j][4];
        const float cyt = scoef[j][5];

        float x = fmaf(cx1, Yg0, fmaf(cx0, Xg, cxt));
        float y = fmaf(cy1, Yg0, fmaf(cy0, Xg, cyt));
        const float dx = cx1 * hstep;
        const float dy = cy1 * hstep;

        float* __restrict__ outp =
            out + ((size_t)(o * BB + b) * (HH * WW)) + h0 * WW + w;

#pragma unroll
        for (int i = 0; i < 16; ++i) {
            const float xc = __builtin_amdgcn_fmed3f(x, 0.0f, hi);
            const float yc = __builtin_amdgcn_fmed3f(y, 0.0f, hi);
            const float x0f = floorf(xc);
            const float y0f = floorf(yc);
            const float wx = xc - x0f;
            const float wy = yc - y0f;
            const int idx = (int)fmaf(y0f, 128.0f, x0f);  // exact (< 2^24)

            const float Ia = img[idx];
            const float Ic = img[idx + 1];        // ds_read2_b32 with Ia
            const float Ib = img[idx + WW];
            const float Id = img[idx + WW + 1];   // ds_read2_b32 with Ib

            const float top = fmaf(wx, Ic - Ia, Ia);
            const float bot = fmaf(wx, Id - Ib, Ib);
            *outp = fmaf(wy, bot - top, top);

            outp += 8 * WW;
            x += dx;
            y += dy;
        }
    }
}

extern "C" void kernel_launch(void* const* d_in, const int* in_sizes, int n_in,
                              void* d_out, int out_size, void* d_ws, size_t ws_size,
                              hipStream_t stream) {
    const float* X    = (const float*)d_in[0];
    const float* eps  = (const float*)d_in[1];
    const float* tmin = (const float*)d_in[2];
    const float* tmax = (const float*)d_in[3];
    float* out = (float*)d_out;

    const int nblocks = BB * 8;  // 512: 2 per CU, LDS-capped full occupancy
    sample_kernel<<<nblocks, 1024, 0, stream>>>(X, eps, tmin, tmax, out);
}